// Round 7
// baseline (440.327 us; speedup 1.0000x reference)
//
#include <hip/hip_runtime.h>
#include <hip/hip_fp8.h>
#include <math.h>

#define NN 3072
#define NU 1024
#define NI 2048
#define DD 128
#define BB 8192
#define GAMMA_F 0.2f

#define SCALE_A 524288.0f                // 2^19
#define F8SCALE2 1.9073486328125e-06f    // 2^-19  (C*2^38 -> A2*2^19 for fp8)
#define DESCALE38 3.637978807091713e-12f // 2^-38  (C -> true A^k values)

typedef __attribute__((ext_vector_type(4))) float f32x4;

// async global->LDS, 16B per lane; LDS dst = wave-uniform base + lane*16
#define GLDS16(g, l)                                                          \
  __builtin_amdgcn_global_load_lds(                                           \
      (__attribute__((address_space(1))) void*)(g),                           \
      (__attribute__((address_space(3))) void*)(l), 16, 0, 0)

static __device__ inline unsigned short bf16bits(float x) {
  union { unsigned u; float f; } cv;
  cv.f = x;
  unsigned r = cv.u + 0x7fff + ((cv.u >> 16) & 1);  // RNE
  return (unsigned short)(r >> 16);
}

// pack 4 floats -> 4 fp8 e4m3 (OCP) bytes
static __device__ inline unsigned pk4_f8(float a, float b, float c, float d) {
#if defined(__has_builtin)
#if __has_builtin(__builtin_amdgcn_cvt_pk_fp8_f32)
  int p = __builtin_amdgcn_cvt_pk_fp8_f32(a, b, 0, false);
  p = __builtin_amdgcn_cvt_pk_fp8_f32(c, d, p, true);
  return (unsigned)p;
#else
  return (unsigned)__hip_fp8_e4m3(a).__x | ((unsigned)__hip_fp8_e4m3(b).__x << 8) |
         ((unsigned)__hip_fp8_e4m3(c).__x << 16) |
         ((unsigned)__hip_fp8_e4m3(d).__x << 24);
#endif
#else
  return (unsigned)__hip_fp8_e4m3(a).__x | ((unsigned)__hip_fp8_e4m3(b).__x << 8) |
         ((unsigned)__hip_fp8_e4m3(c).__x << 16) |
         ((unsigned)__hip_fp8_e4m3(d).__x << 24);
#endif
}

// fast fp32 global atomic add (tiny y1/s1 accumulators only)
static __device__ inline void atomAddF(float* p, float v) {
#if defined(__has_builtin)
#if __has_builtin(__builtin_amdgcn_global_atomic_fadd_f32)
  __builtin_amdgcn_global_atomic_fadd_f32(
      (__attribute__((address_space(1))) float*)p, v);
#else
  unsafeAtomicAdd(p, v);
#endif
#else
  unsafeAtomicAdd(p, v);
#endif
}

static __device__ inline float block_sum(float s, float* red4) {
  int tid = threadIdx.x;
  for (int off = 32; off; off >>= 1) s += __shfl_down(s, off, 64);
  if ((tid & 63) == 0) red4[tid >> 6] = s;
  __syncthreads();
  return red4[0] + red4[1] + red4[2] + red4[3];
}

static __device__ inline float row_dot_f32(const float* __restrict__ a,
                                           const float* __restrict__ b,
                                           float* red4) {
  const float4* ap = (const float4*)a;
  const float4* bp = (const float4*)b;
  float s = 0.f;
  for (int j = threadIdx.x; j < NN / 4; j += 256) {
    float4 x = ap[j], y = bp[j];
    s += x.x * y.x + x.y * y.y + x.z * y.z + x.w * y.w;
  }
  return block_sum(s, red4);
}

// ---------------------------------------------------------------------------
// Per-row top-64 via exact 31-bit radix select; one wave per row.
// bf=1: base is bf16 partials (parts buffers, stride NN*NN ushorts), summed
// in fp32.  bf=0: base is a single fp32 matrix.  tVal scaled by descale;
// optional fused fp8 row output (value * f8scale).
static __device__ void topk_row_dev(const void* __restrict__ base, int parts,
                                    int bf, int row, int lane, float descale,
                                    int* __restrict__ outCnt,
                                    int* __restrict__ outIdx,
                                    float* __restrict__ outVal,
                                    unsigned char* __restrict__ outF8,
                                    float f8scale) {
  float f[48];
  if (bf) {
    const unsigned short* b0 = (const unsigned short*)base;
    const uint4* r0 = (const uint4*)(b0 + (size_t)row * NN);
#pragma unroll
    for (int j = 0; j < 6; ++j) {
      uint4 q = r0[lane + j * 64];
      unsigned uu[4] = {q.x, q.y, q.z, q.w};
#pragma unroll
      for (int e = 0; e < 4; ++e) {
        f[j * 8 + e * 2] = __uint_as_float(uu[e] << 16);
        f[j * 8 + e * 2 + 1] = __uint_as_float(uu[e] & 0xffff0000u);
      }
    }
    for (int p = 1; p < parts; ++p) {
      const uint4* rp =
          (const uint4*)(b0 + (size_t)p * NN * NN + (size_t)row * NN);
#pragma unroll
      for (int j = 0; j < 6; ++j) {
        uint4 q = rp[lane + j * 64];
        unsigned uu[4] = {q.x, q.y, q.z, q.w};
#pragma unroll
        for (int e = 0; e < 4; ++e) {
          f[j * 8 + e * 2] += __uint_as_float(uu[e] << 16);
          f[j * 8 + e * 2 + 1] += __uint_as_float(uu[e] & 0xffff0000u);
        }
      }
    }
  } else {
    const float4* r0 = (const float4*)((const float*)base + (size_t)row * NN);
#pragma unroll
    for (int j = 0; j < 12; ++j) {
      float4 a = r0[lane + j * 64];
      f[j * 4 + 0] = a.x; f[j * 4 + 1] = a.y;
      f[j * 4 + 2] = a.z; f[j * 4 + 3] = a.w;
    }
  }
  if (outF8) {
    // bf path layout: f[j*8+e] = col (j*64+lane)*8 + e
    uint2* ob = (uint2*)(outF8 + (size_t)row * NN);
#pragma unroll
    for (int j = 0; j < 6; ++j) {
      uint2 w;
      w.x = pk4_f8(f[j * 8 + 0] * f8scale, f[j * 8 + 1] * f8scale,
                   f[j * 8 + 2] * f8scale, f[j * 8 + 3] * f8scale);
      w.y = pk4_f8(f[j * 8 + 4] * f8scale, f[j * 8 + 5] * f8scale,
                   f[j * 8 + 6] * f8scale, f[j * 8 + 7] * f8scale);
      ob[lane + j * 64] = w;
    }
  }
  unsigned v[48];
#pragma unroll
  for (int r = 0; r < 48; ++r) v[r] = __float_as_uint(f[r]);

  unsigned t = 0;
  for (int b = 30; b >= 0; --b) {
    unsigned cand = t | (1u << b);
    int c = 0;
#pragma unroll
    for (int r = 0; r < 48; ++r) c += (v[r] >= cand) ? 1 : 0;
    for (int off = 32; off; off >>= 1) c += __shfl_down(c, off, 64);
    c = __shfl(c, 0, 64);
    if (c >= 64) t = cand;
  }
  int basec = 0;
  int* oi = outIdx + (size_t)row * 128;
  float* ov = outVal + (size_t)row * 128;
#pragma unroll
  for (int r = 0; r < 48; ++r) {
    bool keep = v[r] >= t;
    unsigned long long m = __ballot(keep);
    if (keep) {
      int pos = basec + __popcll(m & ((1ull << lane) - 1ull));
      if (pos < 128) {
        oi[pos] = bf ? ((r >> 3) * 512 + lane * 8 + (r & 7))
                     : ((r >> 2) * 256 + lane * 4 + (r & 3));
        ov[pos] = __uint_as_float(v[r]) * descale;
      }
    }
    basec += __popcll(m);
  }
  if (lane == 0) outCnt[row] = basec < 128 ? basec : 128;
}

// ---------------------------------------------------------------------------
// prep: [0,2304) convert A -> fp8 (straight + transposed, x2^19) + fused
//       y1/s1 matvec partials; [2304,3072) topk(A) layer 0.
__global__ __launch_bounds__(256) void prep(
    const float* __restrict__ A, const float* __restrict__ vu,
    const float* __restrict__ vv, unsigned char* __restrict__ Af8,
    unsigned char* __restrict__ Atf8, float* __restrict__ y1,
    float* __restrict__ s1, int* __restrict__ cnts, int* __restrict__ tIdx,
    float* __restrict__ tVal) {
  __shared__ float sh[64 * 65 + 512];
  const int bid = blockIdx.x;
  const int t = threadIdx.x;
  if (bid < 2304) {
    const int bx = (bid % 48) * 64, by = (bid / 48) * 64;
    const int rr = t >> 4;
    const int c4 = (t & 15) * 4;
    for (int it = 0; it < 4; ++it) {
      int r = rr + it * 16;
      float4 val = *(const float4*)(A + (size_t)(by + r) * NN + bx + c4);
      sh[r * 65 + c4] = val.x; sh[r * 65 + c4 + 1] = val.y;
      sh[r * 65 + c4 + 2] = val.z; sh[r * 65 + c4 + 3] = val.w;
      *(unsigned*)(Af8 + (size_t)(by + r) * NN + bx + c4) =
          pk4_f8(val.x * SCALE_A, val.y * SCALE_A, val.z * SCALE_A,
                 val.w * SCALE_A);
    }
    __syncthreads();
    for (int it = 0; it < 4; ++it) {
      int c = (t >> 4) + it * 16;
      int r0 = (t & 15) * 4;
      *(unsigned*)(Atf8 + (size_t)(bx + c) * NN + by + r0) =
          pk4_f8(sh[r0 * 65 + c] * SCALE_A, sh[(r0 + 1) * 65 + c] * SCALE_A,
                 sh[(r0 + 2) * 65 + c] * SCALE_A,
                 sh[(r0 + 3) * 65 + c] * SCALE_A);
    }
    // fused matvec partials: y1[r] += A[r,:].v ; s1[c] += u.A[:,c]
    const int q = t >> 6;
    const int l = t & 63;
    float sy = 0.f, ss_ = 0.f;
    for (int i = 0; i < 16; ++i) {
      int c = q * 16 + i;
      sy += sh[l * 65 + c] * vv[bx + c];
      ss_ += vu[by + c] * sh[c * 65 + l];
    }
    float* red = sh + 64 * 65;
    red[q * 64 + l] = sy;
    red[256 + q * 64 + l] = ss_;
    __syncthreads();
    if (t < 64) {
      float v4 = red[t] + red[64 + t] + red[128 + t] + red[192 + t];
      atomAddF(&y1[by + t], v4);
    } else if (t < 128) {
      int cc = t - 64;
      float v4 = red[256 + cc] + red[256 + 64 + cc] + red[256 + 128 + cc] +
                 red[256 + 192 + cc];
      atomAddF(&s1[bx + cc], v4);
    }
  } else {
    int row = (bid - 2304) * 4 + (t >> 6);
    topk_row_dev(A, 1, 0, row, t & 63, 1.0f, cnts, tIdx, tVal, nullptr, 0.f);
  }
}

// ---------------------------------------------------------------------------
// fp8 GEMM: C(128x128 tile, bf16) = A(row-major fp8) * Bt(row-major fp8=B^T),
// BK=64; split-K over blockIdx.z writing separate bf16 partial buffers.
__global__ __launch_bounds__(256) void gemm_f8(
    const unsigned char* __restrict__ Ag,
    const unsigned char* __restrict__ Btg,
    unsigned short* __restrict__ Cg, int kLen) {
  __shared__ __align__(16) unsigned char As[8192];
  __shared__ __align__(16) unsigned char Bs[8192];

  const int tid = threadIdx.x;
  const int wave = tid >> 6;
  const int lane = tid & 63;
  const int rowBase = blockIdx.y * 128;
  const int colBase = blockIdx.x * 128;
  const int wr = wave >> 1, wc = wave & 1;
  const int lrow = lane & 15, lq = lane >> 4;
  const int kStart = blockIdx.z * kLen;
  unsigned short* Cout = Cg + (size_t)blockIdx.z * NN * NN;

  f32x4 acc[4][4];
  for (int i = 0; i < 4; ++i)
    for (int j = 0; j < 4; ++j) acc[i][j] = (f32x4){0.f, 0.f, 0.f, 0.f};

  const unsigned char* aS0 =
      Ag + (size_t)(rowBase + 2 * wave * 16 + lrow) * NN + lq * 16;
  const unsigned char* aS1 = aS0 + (size_t)16 * NN;
  const unsigned char* bS0 =
      Btg + (size_t)(colBase + 2 * wave * 16 + lrow) * NN + lq * 16;
  const unsigned char* bS1 = bS0 + (size_t)16 * NN;
  unsigned char* aD0 = &As[(2 * wave) * 1024];
  unsigned char* aD1 = &As[(2 * wave + 1) * 1024];
  unsigned char* bD0 = &Bs[(2 * wave) * 1024];
  unsigned char* bD1 = &Bs[(2 * wave + 1) * 1024];

  for (int kt = kStart; kt < kStart + kLen; kt += 64) {
    GLDS16(aS0 + kt, aD0);
    GLDS16(aS1 + kt, aD1);
    GLDS16(bS0 + kt, bD0);
    GLDS16(bS1 + kt, bD1);
    __syncthreads();
    for (int h = 0; h < 2; ++h) {
      const int fo = (h * 2 + (lq >> 1)) * 256 + lrow * 16 + (lq & 1) * 8;
      long af[4], bf[4];
      for (int i = 0; i < 4; ++i)
        af[i] = *(const long*)&As[(wr * 4 + i) * 1024 + fo];
      for (int j = 0; j < 4; ++j)
        bf[j] = *(const long*)&Bs[(wc * 4 + j) * 1024 + fo];
      for (int i = 0; i < 4; ++i)
        for (int j = 0; j < 4; ++j)
          acc[i][j] = __builtin_amdgcn_mfma_f32_16x16x32_fp8_fp8(
              af[i], bf[j], acc[i][j], 0, 0, 0);
    }
    __syncthreads();
  }
  // C/D layout: col = lane&15, row = (lane>>4)*4 + reg (dtype-independent)
  for (int i = 0; i < 4; ++i) {
    int r0 = rowBase + (wr * 4 + i) * 16 + lq * 4;
    for (int j = 0; j < 4; ++j) {
      int c0 = colBase + (wc * 4 + j) * 16 + lrow;
      for (int r = 0; r < 4; ++r)
        Cout[(size_t)(r0 + r) * NN + c0] = bf16bits(acc[i][j][r]);
    }
  }
}

// ---------------------------------------------------------------------------
// post1: [0,768) topk(A2 bf16 partial-sum) + fused fp8 cast -> A2f8
//        [768,1536) tvec = A.y1 (fp32 rows, one wave per row)
__global__ __launch_bounds__(256) void post1(
    const unsigned short* __restrict__ C, int parts,
    const float* __restrict__ A, const float* __restrict__ y1,
    unsigned char* __restrict__ A2f8, int* __restrict__ cnts,
    int* __restrict__ tIdx, float* __restrict__ tVal,
    float* __restrict__ tvec) {
  const int bid = blockIdx.x;
  const int t = threadIdx.x;
  if (bid < 768) {
    int row = bid * 4 + (t >> 6);
    topk_row_dev(C, parts, 1, row, t & 63, DESCALE38, cnts, tIdx, tVal, A2f8,
                 F8SCALE2);
  } else {
    int row = (bid - 768) * 4 + (t >> 6);
    int lane = t & 63;
    const float4* rp = (const float4*)(A + (size_t)row * NN);
    const float4* yp = (const float4*)y1;
    float s = 0.f;
#pragma unroll
    for (int j = 0; j < 12; ++j) {
      float4 a = rp[lane + j * 64];
      float4 y = yp[lane + j * 64];
      s += a.x * y.x + a.y * y.y + a.z * y.z + a.w * y.w;
    }
    for (int off = 32; off; off >>= 1) s += __shfl_down(s, off, 64);
    if (lane == 0) tvec[row] = s;
  }
}

// ---------------------------------------------------------------------------
// post2: [0,768) topk(A3 bf16 partial-sum); [768] w0..w3
__global__ __launch_bounds__(256) void post2(
    const unsigned short* __restrict__ C, int parts,
    const float* __restrict__ vu, const float* __restrict__ vv,
    const float* __restrict__ y1, const float* __restrict__ s1,
    const float* __restrict__ tvec, int* __restrict__ cnts,
    int* __restrict__ tIdx, float* __restrict__ tVal,
    float* __restrict__ wacc) {
  const int bid = blockIdx.x;
  const int t = threadIdx.x;
  if (bid < 768) {
    int row = bid * 4 + (t >> 6);
    topk_row_dev(C, parts, 1, row, t & 63, DESCALE38, cnts, tIdx, tVal,
                 nullptr, 0.f);
  } else {
    __shared__ float red4[4];
    float w0 = row_dot_f32(vu, vv, red4);  __syncthreads();
    float w1 = row_dot_f32(vu, y1, red4);  __syncthreads();
    float w2 = row_dot_f32(s1, y1, red4);  __syncthreads();
    float w3 = row_dot_f32(s1, tvec, red4);
    if (t == 0) { wacc[0] = w0; wacc[1] = w1; wacc[2] = w2; wacc[3] = w3; }
  }
}

// ---------------------------------------------------------------------------
static __device__ inline float ldE(const float* __restrict__ ue,
                                   const float* __restrict__ ie, int r, int d) {
  return r < NU ? ue[(size_t)r * DD + d] : ie[(size_t)(r - NU) * DD + d];
}

__global__ __launch_bounds__(128) void build_light(
    const float* __restrict__ uemb, const float* __restrict__ iemb,
    const float* __restrict__ uemb0, const float* __restrict__ iemb0,
    const float* __restrict__ wacc, const int* __restrict__ cnts,
    const int* __restrict__ tIdx, const float* __restrict__ tVal,
    float* __restrict__ lightOut) {
  float w0 = wacc[0], w1 = wacc[1], w2 = wacc[2], w3 = wacc[3];
  float ss = w0 + w1 + w2 + w3;
  w0 /= ss; w1 /= ss; w2 /= ss; w3 /= ss;
  float m = fmaxf(fmaxf(w0, w1), fmaxf(w2, w3));
  float e0 = expf(w0 - m), e1 = expf(w1 - m), e2 = expf(w2 - m),
        e3 = expf(w3 - m);
  float se = e0 + e1 + e2 + e3;
  float aw[4] = {e0 / se, e1 / se, e2 / se, e3 / se};
  float aw4 = GAMMA_F * (aw[1] + aw[2] + aw[3]);

  int row = blockIdx.x, d = threadIdx.x;
  float acc = aw[0] * ldE(uemb, iemb, row, d) +
              aw4 * ldE(uemb0, iemb0, row, d);
  __shared__ int sIdx[128];
  __shared__ float sVal[128];
  for (int l = 0; l < 3; ++l) {
    int c = cnts[l * NN + row];
    const int* ip = tIdx + ((size_t)l * NN + row) * 128;
    const float* vp = tVal + ((size_t)l * NN + row) * 128;
    __syncthreads();
    if (d < c) { sIdx[d] = ip[d]; sVal[d] = vp[d]; }
    __syncthreads();
    float al = aw[l + 1];
    float la = 0.f;
    for (int k = 0; k < c; ++k) la += sVal[k] * ldE(uemb, iemb, sIdx[k], d);
    acc += al * la;
  }
  lightOut[(size_t)row * DD + d] = acc;
}

__global__ __launch_bounds__(256) void out_dot(const int* __restrict__ users,
                                               const int* __restrict__ items,
                                               const float* __restrict__ lightOut,
                                               float* __restrict__ out) {
  int b = blockIdx.x * 4 + (threadIdx.x >> 6);
  int lane = threadIdx.x & 63;
  const float* up = lightOut + (size_t)users[b] * DD;
  const float* ip = lightOut + (size_t)(NU + items[b]) * DD;
  float s = up[lane] * ip[lane] + up[lane + 64] * ip[lane + 64];
  for (int off = 32; off; off >>= 1) s += __shfl_down(s, off, 64);
  if (lane == 0) out[b] = s;
}

// ---------------------------------------------------------------------------
extern "C" void kernel_launch(void* const* d_in, const int* in_sizes, int n_in,
                              void* d_out, int out_size, void* d_ws,
                              size_t ws_size, hipStream_t stream) {
  const int* users = (const int*)d_in[0];
  const int* items = (const int*)d_in[1];
  const float* A = (const float*)d_in[2];
  const float* uemb = (const float*)d_in[3];
  const float* iemb = (const float*)d_in[4];
  const float* uemb0 = (const float*)d_in[5];
  const float* iemb0 = (const float*)d_in[6];
  const float* vu = (const float*)d_in[7];
  const float* vv = (const float*)d_in[8];
  float* out = (float*)d_out;

  char* ws = (char*)d_ws;
  size_t off = 0;
  auto alloc = [&](size_t bytes) -> void* {
    void* p = ws + off;
    off += (bytes + 255) & ~(size_t)255;
    return p;
  };
  unsigned char* Af8 = (unsigned char*)alloc((size_t)NN * NN);
  unsigned char* Atf8 = (unsigned char*)alloc((size_t)NN * NN);
  unsigned char* A2f8 = (unsigned char*)alloc((size_t)NN * NN);
  float* y1 = (float*)alloc((size_t)NN * 4);   // contiguous with s1
  float* s1 = (float*)alloc((size_t)NN * 4);
  float* tvec = (float*)alloc((size_t)NN * 4);
  float* wacc = (float*)alloc(256);
  int* cnts = (int*)alloc((size_t)3 * NN * 4);
  int* tIdx = (int*)alloc((size_t)3 * NN * 128 * 4);
  float* tVal = (float*)alloc((size_t)3 * NN * 128 * 4);
  float* lightOut = (float*)alloc((size_t)NN * DD * 4);

  const size_t cBytes = (size_t)NN * NN * 2;  // bf16 partials
  int kParts = 1;
  if (ws_size >= off + 4 * cBytes + 512) kParts = 4;
  else if (ws_size >= off + 2 * cBytes + 512) kParts = 2;
  unsigned short* C = (unsigned short*)alloc((size_t)kParts * cBytes);
  const int kLen = NN / kParts;

  // 1) zero y1/s1 (contiguous 2*NN floats)
  hipMemsetAsync(y1, 0, (size_t)2 * NN * 4, stream);
  // 2) prep: A -> fp8 (straight+transposed) + y1/s1 partials | topk(A)
  prep<<<3072, 256, 0, stream>>>(A, vu, vv, Af8, Atf8, y1, s1, cnts, tIdx,
                                 tVal);
  // 3) A2 = A*A (fp8 MFMA, bf16 partials)
  gemm_f8<<<dim3(24, 24, kParts), 256, 0, stream>>>(Af8, Atf8, C, kLen);
  // 4) post1: topk(A2)+fp8 cast | tvec = A.y1
  post1<<<1536, 256, 0, stream>>>(C, kParts, A, y1, A2f8, cnts + NN,
                                  tIdx + (size_t)NN * 128,
                                  tVal + (size_t)NN * 128, tvec);
  // 5) A3 = A2*A (overwrite partials)
  gemm_f8<<<dim3(24, 24, kParts), 256, 0, stream>>>(A2f8, Atf8, C, kLen);
  // 6) post2: topk(A3) | w0..w3
  post2<<<769, 256, 0, stream>>>(C, kParts, vu, vv, y1, s1, tvec,
                                 cnts + 2 * NN, tIdx + (size_t)2 * NN * 128,
                                 tVal + (size_t)2 * NN * 128, wacc);
  // 7) light_out (attn softmax inlined)
  build_light<<<NN, 128, 0, stream>>>(uemb, iemb, uemb0, iemb0, wacc, cnts,
                                      tIdx, tVal, lightOut);
  // 8) gather dots
  out_dot<<<BB / 4, 256, 0, stream>>>(users, items, lightOut, out);
}

// Round 8
// 398.919 us; speedup vs baseline: 1.1038x; 1.1038x over previous
//
#include <hip/hip_runtime.h>
#include <hip/hip_fp8.h>
#include <math.h>

#define NN 3072
#define NU 1024
#define NI 2048
#define DD 128
#define BB 8192
#define GAMMA_F 0.2f

#define SCALE_A 524288.0f                // 2^19
#define F8SCALE2 1.9073486328125e-06f    // 2^-19  (C*2^38 -> A2*2^19 for fp8)
#define DESCALE38 3.637978807091713e-12f // 2^-38  (C -> true A^k values)

typedef __attribute__((ext_vector_type(4))) float f32x4;

// async global->LDS, 16B per lane; LDS dst = wave-uniform base + lane*16
#define GLDS16(g, l)                                                          \
  __builtin_amdgcn_global_load_lds(                                           \
      (__attribute__((address_space(1))) void*)(g),                           \
      (__attribute__((address_space(3))) void*)(l), 16, 0, 0)

static __device__ inline unsigned short bf16bits(float x) {
  union { unsigned u; float f; } cv;
  cv.f = x;
  unsigned r = cv.u + 0x7fff + ((cv.u >> 16) & 1);  // RNE
  return (unsigned short)(r >> 16);
}

// pack 4 floats -> 4 fp8 e4m3 (OCP) bytes
static __device__ inline unsigned pk4_f8(float a, float b, float c, float d) {
#if defined(__has_builtin)
#if __has_builtin(__builtin_amdgcn_cvt_pk_fp8_f32)
  int p = __builtin_amdgcn_cvt_pk_fp8_f32(a, b, 0, false);
  p = __builtin_amdgcn_cvt_pk_fp8_f32(c, d, p, true);
  return (unsigned)p;
#else
  return (unsigned)__hip_fp8_e4m3(a).__x | ((unsigned)__hip_fp8_e4m3(b).__x << 8) |
         ((unsigned)__hip_fp8_e4m3(c).__x << 16) |
         ((unsigned)__hip_fp8_e4m3(d).__x << 24);
#endif
#else
  return (unsigned)__hip_fp8_e4m3(a).__x | ((unsigned)__hip_fp8_e4m3(b).__x << 8) |
         ((unsigned)__hip_fp8_e4m3(c).__x << 16) |
         ((unsigned)__hip_fp8_e4m3(d).__x << 24);
#endif
}

// fast fp32 global atomic add (tiny y1/s1 accumulators only)
static __device__ inline void atomAddF(float* p, float v) {
#if defined(__has_builtin)
#if __has_builtin(__builtin_amdgcn_global_atomic_fadd_f32)
  __builtin_amdgcn_global_atomic_fadd_f32(
      (__attribute__((address_space(1))) float*)p, v);
#else
  unsafeAtomicAdd(p, v);
#endif
#else
  unsafeAtomicAdd(p, v);
#endif
}

static __device__ inline float block_sum(float s, float* red4) {
  int tid = threadIdx.x;
  for (int off = 32; off; off >>= 1) s += __shfl_down(s, off, 64);
  if ((tid & 63) == 0) red4[tid >> 6] = s;
  __syncthreads();
  return red4[0] + red4[1] + red4[2] + red4[3];
}

static __device__ inline float row_dot_f32(const float* __restrict__ a,
                                           const float* __restrict__ b,
                                           float* red4) {
  const float4* ap = (const float4*)a;
  const float4* bp = (const float4*)b;
  float s = 0.f;
  for (int j = threadIdx.x; j < NN / 4; j += 256) {
    float4 x = ap[j], y = bp[j];
    s += x.x * y.x + x.y * y.y + x.z * y.z + x.w * y.w;
  }
  return block_sum(s, red4);
}

// ---------------------------------------------------------------------------
// Per-row top-64 via exact radix select over bits [30..lowbit]; one wave/row.
// bf=1: base = bf16 partials (parts buffers, stride NN*NN ushorts, low 16
// bits of each value are zero -> lowbit=16 stays exact). bf=0: fp32 matrix.
static __device__ void topk_row_dev(const void* __restrict__ base, int parts,
                                    int bf, int lowbit, int row, int lane,
                                    float descale, int* __restrict__ outCnt,
                                    int* __restrict__ outIdx,
                                    float* __restrict__ outVal,
                                    unsigned char* __restrict__ outF8,
                                    float f8scale) {
  float f[48];
  if (bf) {
    const unsigned short* b0 = (const unsigned short*)base;
    const uint4* r0 = (const uint4*)(b0 + (size_t)row * NN);
#pragma unroll
    for (int j = 0; j < 6; ++j) {
      uint4 q = r0[lane + j * 64];
      unsigned uu[4] = {q.x, q.y, q.z, q.w};
#pragma unroll
      for (int e = 0; e < 4; ++e) {
        f[j * 8 + e * 2] = __uint_as_float(uu[e] << 16);
        f[j * 8 + e * 2 + 1] = __uint_as_float(uu[e] & 0xffff0000u);
      }
    }
    for (int p = 1; p < parts; ++p) {
      const uint4* rp =
          (const uint4*)(b0 + (size_t)p * NN * NN + (size_t)row * NN);
#pragma unroll
      for (int j = 0; j < 6; ++j) {
        uint4 q = rp[lane + j * 64];
        unsigned uu[4] = {q.x, q.y, q.z, q.w};
#pragma unroll
        for (int e = 0; e < 4; ++e) {
          f[j * 8 + e * 2] += __uint_as_float(uu[e] << 16);
          f[j * 8 + e * 2 + 1] += __uint_as_float(uu[e] & 0xffff0000u);
        }
      }
    }
  } else {
    const float4* r0 = (const float4*)((const float*)base + (size_t)row * NN);
#pragma unroll
    for (int j = 0; j < 12; ++j) {
      float4 a = r0[lane + j * 64];
      f[j * 4 + 0] = a.x; f[j * 4 + 1] = a.y;
      f[j * 4 + 2] = a.z; f[j * 4 + 3] = a.w;
    }
  }
  if (outF8) {
    // bf path layout: f[j*8+e] = col (j*64+lane)*8 + e
    uint2* ob = (uint2*)(outF8 + (size_t)row * NN);
#pragma unroll
    for (int j = 0; j < 6; ++j) {
      uint2 w;
      w.x = pk4_f8(f[j * 8 + 0] * f8scale, f[j * 8 + 1] * f8scale,
                   f[j * 8 + 2] * f8scale, f[j * 8 + 3] * f8scale);
      w.y = pk4_f8(f[j * 8 + 4] * f8scale, f[j * 8 + 5] * f8scale,
                   f[j * 8 + 6] * f8scale, f[j * 8 + 7] * f8scale);
      ob[lane + j * 64] = w;
    }
  }
  unsigned v[48];
#pragma unroll
  for (int r = 0; r < 48; ++r) v[r] = __float_as_uint(f[r]);

  unsigned t = 0;
  for (int b = 30; b >= lowbit; --b) {
    unsigned cand = t | (1u << b);
    int c = 0;
#pragma unroll
    for (int r = 0; r < 48; ++r) c += (v[r] >= cand) ? 1 : 0;
    for (int off = 32; off; off >>= 1) c += __shfl_down(c, off, 64);
    c = __shfl(c, 0, 64);
    if (c >= 64) t = cand;
  }
  int basec = 0;
  int* oi = outIdx + (size_t)row * 128;
  float* ov = outVal + (size_t)row * 128;
#pragma unroll
  for (int r = 0; r < 48; ++r) {
    bool keep = v[r] >= t;
    unsigned long long m = __ballot(keep);
    if (keep) {
      int pos = basec + __popcll(m & ((1ull << lane) - 1ull));
      if (pos < 128) {
        oi[pos] = bf ? ((r >> 3) * 512 + lane * 8 + (r & 7))
                     : ((r >> 2) * 256 + lane * 4 + (r & 3));
        ov[pos] = __uint_as_float(v[r]) * descale;
      }
    }
    basec += __popcll(m);
  }
  if (lane == 0) outCnt[row] = basec < 128 ? basec : 128;
}

// ---------------------------------------------------------------------------
// prep: convert A -> fp8 (straight + transposed, x2^19) + fused y1/s1
// matvec partials. grid 2304 (48x48 tiles of 64x64). Conv-only: low VGPR.
__global__ __launch_bounds__(256) void prep(
    const float* __restrict__ A, const float* __restrict__ vu,
    const float* __restrict__ vv, unsigned char* __restrict__ Af8,
    unsigned char* __restrict__ Atf8, float* __restrict__ y1,
    float* __restrict__ s1) {
  __shared__ float sh[64 * 65 + 512];
  const int bid = blockIdx.x;
  const int t = threadIdx.x;
  const int bx = (bid % 48) * 64, by = (bid / 48) * 64;
  const int rr = t >> 4;
  const int c4 = (t & 15) * 4;
  for (int it = 0; it < 4; ++it) {
    int r = rr + it * 16;
    float4 val = *(const float4*)(A + (size_t)(by + r) * NN + bx + c4);
    sh[r * 65 + c4] = val.x; sh[r * 65 + c4 + 1] = val.y;
    sh[r * 65 + c4 + 2] = val.z; sh[r * 65 + c4 + 3] = val.w;
    *(unsigned*)(Af8 + (size_t)(by + r) * NN + bx + c4) =
        pk4_f8(val.x * SCALE_A, val.y * SCALE_A, val.z * SCALE_A,
               val.w * SCALE_A);
  }
  __syncthreads();
  for (int it = 0; it < 4; ++it) {
    int c = (t >> 4) + it * 16;
    int r0 = (t & 15) * 4;
    *(unsigned*)(Atf8 + (size_t)(bx + c) * NN + by + r0) =
        pk4_f8(sh[r0 * 65 + c] * SCALE_A, sh[(r0 + 1) * 65 + c] * SCALE_A,
               sh[(r0 + 2) * 65 + c] * SCALE_A,
               sh[(r0 + 3) * 65 + c] * SCALE_A);
  }
  // fused matvec partials: y1[r] += A[r,:].v ; s1[c] += u.A[:,c]
  const int q = t >> 6;
  const int l = t & 63;
  float sy = 0.f, ss_ = 0.f;
  for (int i = 0; i < 16; ++i) {
    int c = q * 16 + i;
    sy += sh[l * 65 + c] * vv[bx + c];
    ss_ += vu[by + c] * sh[c * 65 + l];
  }
  float* red = sh + 64 * 65;
  red[q * 64 + l] = sy;
  red[256 + q * 64 + l] = ss_;
  __syncthreads();
  if (t < 64) {
    float v4 = red[t] + red[64 + t] + red[128 + t] + red[192 + t];
    atomAddF(&y1[by + t], v4);
  } else if (t < 128) {
    int cc = t - 64;
    float v4 = red[256 + cc] + red[256 + 64 + cc] + red[256 + 128 + cc] +
               red[256 + 192 + cc];
    atomAddF(&s1[bx + cc], v4);
  }
}

// ---------------------------------------------------------------------------
// fp8 GEMM: C(128x128 tile, bf16) = A(row-major fp8) * Bt(row-major fp8=B^T),
// BK=64; split-K over blockIdx.z writing separate bf16 partial buffers.
__global__ __launch_bounds__(256) void gemm_f8(
    const unsigned char* __restrict__ Ag,
    const unsigned char* __restrict__ Btg,
    unsigned short* __restrict__ Cg, int kLen) {
  __shared__ __align__(16) unsigned char As[8192];
  __shared__ __align__(16) unsigned char Bs[8192];

  const int tid = threadIdx.x;
  const int wave = tid >> 6;
  const int lane = tid & 63;
  const int rowBase = blockIdx.y * 128;
  const int colBase = blockIdx.x * 128;
  const int wr = wave >> 1, wc = wave & 1;
  const int lrow = lane & 15, lq = lane >> 4;
  const int kStart = blockIdx.z * kLen;
  unsigned short* Cout = Cg + (size_t)blockIdx.z * NN * NN;

  f32x4 acc[4][4];
  for (int i = 0; i < 4; ++i)
    for (int j = 0; j < 4; ++j) acc[i][j] = (f32x4){0.f, 0.f, 0.f, 0.f};

  const unsigned char* aS0 =
      Ag + (size_t)(rowBase + 2 * wave * 16 + lrow) * NN + lq * 16;
  const unsigned char* aS1 = aS0 + (size_t)16 * NN;
  const unsigned char* bS0 =
      Btg + (size_t)(colBase + 2 * wave * 16 + lrow) * NN + lq * 16;
  const unsigned char* bS1 = bS0 + (size_t)16 * NN;
  unsigned char* aD0 = &As[(2 * wave) * 1024];
  unsigned char* aD1 = &As[(2 * wave + 1) * 1024];
  unsigned char* bD0 = &Bs[(2 * wave) * 1024];
  unsigned char* bD1 = &Bs[(2 * wave + 1) * 1024];

  for (int kt = kStart; kt < kStart + kLen; kt += 64) {
    GLDS16(aS0 + kt, aD0);
    GLDS16(aS1 + kt, aD1);
    GLDS16(bS0 + kt, bD0);
    GLDS16(bS1 + kt, bD1);
    __syncthreads();
    for (int h = 0; h < 2; ++h) {
      const int fo = (h * 2 + (lq >> 1)) * 256 + lrow * 16 + (lq & 1) * 8;
      long af[4], bf[4];
      for (int i = 0; i < 4; ++i)
        af[i] = *(const long*)&As[(wr * 4 + i) * 1024 + fo];
      for (int j = 0; j < 4; ++j)
        bf[j] = *(const long*)&Bs[(wc * 4 + j) * 1024 + fo];
      for (int i = 0; i < 4; ++i)
        for (int j = 0; j < 4; ++j)
          acc[i][j] = __builtin_amdgcn_mfma_f32_16x16x32_fp8_fp8(
              af[i], bf[j], acc[i][j], 0, 0, 0);
    }
    __syncthreads();
  }
  // C/D layout: col = lane&15, row = (lane>>4)*4 + reg (dtype-independent)
  for (int i = 0; i < 4; ++i) {
    int r0 = rowBase + (wr * 4 + i) * 16 + lq * 4;
    for (int j = 0; j < 4; ++j) {
      int c0 = colBase + (wc * 4 + j) * 16 + lrow;
      for (int r = 0; r < 4; ++r)
        Cout[(size_t)(r0 + r) * NN + c0] = bf16bits(acc[i][j][r]);
    }
  }
}

// ---------------------------------------------------------------------------
// post1: [0,768)    topk(A2 bf16 partial-sum, 15-round) + fp8 cast -> A2f8
//        [768,1536) topk(A fp32, 31-round)  (layer 0)
//        [1536,2304) tvec = A.y1 (one wave per row)
__global__ __launch_bounds__(256) void post1(
    const unsigned short* __restrict__ C, int parts,
    const float* __restrict__ A, const float* __restrict__ y1,
    unsigned char* __restrict__ A2f8, int* __restrict__ cnts,
    int* __restrict__ tIdx, float* __restrict__ tVal,
    float* __restrict__ tvec) {
  const int bid = blockIdx.x;
  const int t = threadIdx.x;
  if (bid < 768) {
    int row = bid * 4 + (t >> 6);
    topk_row_dev(C, parts, 1, 16, row, t & 63, DESCALE38, cnts + NN,
                 tIdx + (size_t)NN * 128, tVal + (size_t)NN * 128, A2f8,
                 F8SCALE2);
  } else if (bid < 1536) {
    int row = (bid - 768) * 4 + (t >> 6);
    topk_row_dev(A, 1, 0, 0, row, t & 63, 1.0f, cnts, tIdx, tVal, nullptr,
                 0.f);
  } else {
    int row = (bid - 1536) * 4 + (t >> 6);
    int lane = t & 63;
    const float4* rp = (const float4*)(A + (size_t)row * NN);
    const float4* yp = (const float4*)y1;
    float s = 0.f;
#pragma unroll
    for (int j = 0; j < 12; ++j) {
      float4 a = rp[lane + j * 64];
      float4 y = yp[lane + j * 64];
      s += a.x * y.x + a.y * y.y + a.z * y.z + a.w * y.w;
    }
    for (int off = 32; off; off >>= 1) s += __shfl_down(s, off, 64);
    if (lane == 0) tvec[row] = s;
  }
}

// ---------------------------------------------------------------------------
// post2: [0,768) topk(A3 bf16 partial-sum, 15-round); [768] w0..w3
__global__ __launch_bounds__(256) void post2(
    const unsigned short* __restrict__ C, int parts,
    const float* __restrict__ vu, const float* __restrict__ vv,
    const float* __restrict__ y1, const float* __restrict__ s1,
    const float* __restrict__ tvec, int* __restrict__ cnts,
    int* __restrict__ tIdx, float* __restrict__ tVal,
    float* __restrict__ wacc) {
  const int bid = blockIdx.x;
  const int t = threadIdx.x;
  if (bid < 768) {
    int row = bid * 4 + (t >> 6);
    topk_row_dev(C, parts, 1, 16, row, t & 63, DESCALE38, cnts, tIdx, tVal,
                 nullptr, 0.f);
  } else {
    __shared__ float red4[4];
    float w0 = row_dot_f32(vu, vv, red4);  __syncthreads();
    float w1 = row_dot_f32(vu, y1, red4);  __syncthreads();
    float w2 = row_dot_f32(s1, y1, red4);  __syncthreads();
    float w3 = row_dot_f32(s1, tvec, red4);
    if (t == 0) { wacc[0] = w0; wacc[1] = w1; wacc[2] = w2; wacc[3] = w3; }
  }
}

// ---------------------------------------------------------------------------
static __device__ inline float ldE(const float* __restrict__ ue,
                                   const float* __restrict__ ie, int r, int d) {
  return r < NU ? ue[(size_t)r * DD + d] : ie[(size_t)(r - NU) * DD + d];
}

__global__ __launch_bounds__(128) void build_light(
    const float* __restrict__ uemb, const float* __restrict__ iemb,
    const float* __restrict__ uemb0, const float* __restrict__ iemb0,
    const float* __restrict__ wacc, const int* __restrict__ cnts,
    const int* __restrict__ tIdx, const float* __restrict__ tVal,
    float* __restrict__ lightOut) {
  float w0 = wacc[0], w1 = wacc[1], w2 = wacc[2], w3 = wacc[3];
  float ss = w0 + w1 + w2 + w3;
  w0 /= ss; w1 /= ss; w2 /= ss; w3 /= ss;
  float m = fmaxf(fmaxf(w0, w1), fmaxf(w2, w3));
  float e0 = expf(w0 - m), e1 = expf(w1 - m), e2 = expf(w2 - m),
        e3 = expf(w3 - m);
  float se = e0 + e1 + e2 + e3;
  float aw[4] = {e0 / se, e1 / se, e2 / se, e3 / se};
  float aw4 = GAMMA_F * (aw[1] + aw[2] + aw[3]);

  int row = blockIdx.x, d = threadIdx.x;
  float acc = aw[0] * ldE(uemb, iemb, row, d) +
              aw4 * ldE(uemb0, iemb0, row, d);
  __shared__ int sIdx[128];
  __shared__ float sVal[128];
  for (int l = 0; l < 3; ++l) {
    int c = cnts[l * NN + row];
    const int* ip = tIdx + ((size_t)l * NN + row) * 128;
    const float* vp = tVal + ((size_t)l * NN + row) * 128;
    __syncthreads();
    if (d < c) { sIdx[d] = ip[d]; sVal[d] = vp[d]; }
    __syncthreads();
    float al = aw[l + 1];
    float la = 0.f;
    for (int k = 0; k < c; ++k) la += sVal[k] * ldE(uemb, iemb, sIdx[k], d);
    acc += al * la;
  }
  lightOut[(size_t)row * DD + d] = acc;
}

__global__ __launch_bounds__(256) void out_dot(const int* __restrict__ users,
                                               const int* __restrict__ items,
                                               const float* __restrict__ lightOut,
                                               float* __restrict__ out) {
  int b = blockIdx.x * 4 + (threadIdx.x >> 6);
  int lane = threadIdx.x & 63;
  const float* up = lightOut + (size_t)users[b] * DD;
  const float* ip = lightOut + (size_t)(NU + items[b]) * DD;
  float s = up[lane] * ip[lane] + up[lane + 64] * ip[lane + 64];
  for (int off = 32; off; off >>= 1) s += __shfl_down(s, off, 64);
  if (lane == 0) out[b] = s;
}

// ---------------------------------------------------------------------------
extern "C" void kernel_launch(void* const* d_in, const int* in_sizes, int n_in,
                              void* d_out, int out_size, void* d_ws,
                              size_t ws_size, hipStream_t stream) {
  const int* users = (const int*)d_in[0];
  const int* items = (const int*)d_in[1];
  const float* A = (const float*)d_in[2];
  const float* uemb = (const float*)d_in[3];
  const float* iemb = (const float*)d_in[4];
  const float* uemb0 = (const float*)d_in[5];
  const float* iemb0 = (const float*)d_in[6];
  const float* vu = (const float*)d_in[7];
  const float* vv = (const float*)d_in[8];
  float* out = (float*)d_out;

  char* ws = (char*)d_ws;
  size_t off = 0;
  auto alloc = [&](size_t bytes) -> void* {
    void* p = ws + off;
    off += (bytes + 255) & ~(size_t)255;
    return p;
  };
  unsigned char* Af8 = (unsigned char*)alloc((size_t)NN * NN);
  unsigned char* Atf8 = (unsigned char*)alloc((size_t)NN * NN);
  unsigned char* A2f8 = (unsigned char*)alloc((size_t)NN * NN);
  float* y1 = (float*)alloc((size_t)NN * 4);   // contiguous with s1
  float* s1 = (float*)alloc((size_t)NN * 4);
  float* tvec = (float*)alloc((size_t)NN * 4);
  float* wacc = (float*)alloc(256);
  int* cnts = (int*)alloc((size_t)3 * NN * 4);
  int* tIdx = (int*)alloc((size_t)3 * NN * 128 * 4);
  float* tVal = (float*)alloc((size_t)3 * NN * 128 * 4);
  float* lightOut = (float*)alloc((size_t)NN * DD * 4);

  const size_t cBytes = (size_t)NN * NN * 2;  // bf16 partials
  int kParts = (ws_size >= off + 2 * cBytes + 512) ? 2 : 1;
  unsigned short* C = (unsigned short*)alloc((size_t)kParts * cBytes);
  const int kLen = NN / kParts;

  // 1) zero y1/s1 (contiguous 2*NN floats)
  hipMemsetAsync(y1, 0, (size_t)2 * NN * 4, stream);
  // 2) prep: A -> fp8 (straight+transposed) + y1/s1 partials (conv-only)
  prep<<<2304, 256, 0, stream>>>(A, vu, vv, Af8, Atf8, y1, s1);
  // 3) A2 = A*A (fp8 MFMA, bf16 partials x2)
  gemm_f8<<<dim3(24, 24, kParts), 256, 0, stream>>>(Af8, Atf8, C, kLen);
  // 4) post1: topk(A2)+fp8 cast | topk(A) | tvec = A.y1
  post1<<<2304, 256, 0, stream>>>(C, kParts, A, y1, A2f8, cnts, tIdx, tVal,
                                  tvec);
  // 5) A3 = A2*A (overwrite partials)
  gemm_f8<<<dim3(24, 24, kParts), 256, 0, stream>>>(A2f8, Atf8, C, kLen);
  // 6) post2: topk(A3) | w0..w3
  post2<<<769, 256, 0, stream>>>(C, kParts, vu, vv, y1, s1, tvec,
                                 cnts + 2 * NN, tIdx + (size_t)2 * NN * 128,
                                 tVal + (size_t)2 * NN * 128, wacc);
  // 7) light_out (attn softmax inlined)
  build_light<<<NN, 128, 0, stream>>>(uemb, iemb, uemb0, iemb0, wacc, cnts,
                                      tIdx, tVal, lightOut);
  // 8) gather dots
  out_dot<<<BB / 4, 256, 0, stream>>>(users, items, lightOut, out);
}

// Round 9
// 347.141 us; speedup vs baseline: 1.2684x; 1.1492x over previous
//
#include <hip/hip_runtime.h>
#include <hip/hip_fp8.h>
#include <math.h>

#define NN 3072
#define NU 1024
#define NI 2048
#define DD 128
#define BB 8192
#define GAMMA_F 0.2f

#define SCALE_A 524288.0f                // 2^19
#define F8SCALE2 1.9073486328125e-06f    // 2^-19  (C*2^38 -> A2*2^19 for fp8)
#define DESCALE38 3.637978807091713e-12f // 2^-38  (C -> true A^k values)

typedef __attribute__((ext_vector_type(4))) float f32x4;

// async global->LDS, 16B per lane; LDS dst = wave-uniform base + lane*16
#define GLDS16(g, l)                                                          \
  __builtin_amdgcn_global_load_lds(                                           \
      (__attribute__((address_space(1))) void*)(g),                           \
      (__attribute__((address_space(3))) void*)(l), 16, 0, 0)

static __device__ inline unsigned short bf16bits(float x) {
  union { unsigned u; float f; } cv;
  cv.f = x;
  unsigned r = cv.u + 0x7fff + ((cv.u >> 16) & 1);  // RNE
  return (unsigned short)(r >> 16);
}

// pack 4 floats -> 4 fp8 e4m3 (OCP) bytes
static __device__ inline unsigned pk4_f8(float a, float b, float c, float d) {
#if defined(__has_builtin)
#if __has_builtin(__builtin_amdgcn_cvt_pk_fp8_f32)
  int p = __builtin_amdgcn_cvt_pk_fp8_f32(a, b, 0, false);
  p = __builtin_amdgcn_cvt_pk_fp8_f32(c, d, p, true);
  return (unsigned)p;
#else
  return (unsigned)__hip_fp8_e4m3(a).__x | ((unsigned)__hip_fp8_e4m3(b).__x << 8) |
         ((unsigned)__hip_fp8_e4m3(c).__x << 16) |
         ((unsigned)__hip_fp8_e4m3(d).__x << 24);
#endif
#else
  return (unsigned)__hip_fp8_e4m3(a).__x | ((unsigned)__hip_fp8_e4m3(b).__x << 8) |
         ((unsigned)__hip_fp8_e4m3(c).__x << 16) |
         ((unsigned)__hip_fp8_e4m3(d).__x << 24);
#endif
}

// fast fp32 global atomic add (tiny y1/s1 accumulators only)
static __device__ inline void atomAddF(float* p, float v) {
#if defined(__has_builtin)
#if __has_builtin(__builtin_amdgcn_global_atomic_fadd_f32)
  __builtin_amdgcn_global_atomic_fadd_f32(
      (__attribute__((address_space(1))) float*)p, v);
#else
  unsafeAtomicAdd(p, v);
#endif
#else
  unsafeAtomicAdd(p, v);
#endif
}

static __device__ inline float block_sum(float s, float* red4) {
  int tid = threadIdx.x;
  for (int off = 32; off; off >>= 1) s += __shfl_down(s, off, 64);
  if ((tid & 63) == 0) red4[tid >> 6] = s;
  __syncthreads();
  return red4[0] + red4[1] + red4[2] + red4[3];
}

static __device__ inline float row_dot_f32(const float* __restrict__ a,
                                           const float* __restrict__ b,
                                           float* red4) {
  const float4* ap = (const float4*)a;
  const float4* bp = (const float4*)b;
  float s = 0.f;
  for (int j = threadIdx.x; j < NN / 4; j += 256) {
    float4 x = ap[j], y = bp[j];
    s += x.x * y.x + x.y * y.y + x.z * y.z + x.w * y.w;
  }
  return block_sum(s, red4);
}

// ---------------------------------------------------------------------------
// Per-row top-64 via radix select on the 15-bit key prefix (bits 30..16);
// one wave per row; no v[] shadow copy (keys are f's own bits); wave OR/AND
// prefix-skip starts the walk at the highest varying bit.
// bf=1: base = bf16 partials (parts buffers, stride NN*NN ushorts).
// bf=0: single fp32 matrix. tVal = exact f * descale for selected entries.
static __device__ void topk_row_dev(const void* __restrict__ base, int parts,
                                    int bf, int row, int lane, float descale,
                                    int* __restrict__ outCnt,
                                    int* __restrict__ outIdx,
                                    float* __restrict__ outVal,
                                    unsigned char* __restrict__ outF8,
                                    float f8scale) {
  float f[48];
  if (bf) {
    const unsigned short* b0 = (const unsigned short*)base;
    const uint4* r0 = (const uint4*)(b0 + (size_t)row * NN);
#pragma unroll
    for (int j = 0; j < 6; ++j) {
      uint4 q = r0[lane + j * 64];
      unsigned uu[4] = {q.x, q.y, q.z, q.w};
#pragma unroll
      for (int e = 0; e < 4; ++e) {
        f[j * 8 + e * 2] = __uint_as_float(uu[e] << 16);
        f[j * 8 + e * 2 + 1] = __uint_as_float(uu[e] & 0xffff0000u);
      }
    }
    for (int p = 1; p < parts; ++p) {
      const uint4* rp =
          (const uint4*)(b0 + (size_t)p * NN * NN + (size_t)row * NN);
#pragma unroll
      for (int j = 0; j < 6; ++j) {
        uint4 q = rp[lane + j * 64];
        unsigned uu[4] = {q.x, q.y, q.z, q.w};
#pragma unroll
        for (int e = 0; e < 4; ++e) {
          f[j * 8 + e * 2] += __uint_as_float(uu[e] << 16);
          f[j * 8 + e * 2 + 1] += __uint_as_float(uu[e] & 0xffff0000u);
        }
      }
    }
  } else {
    const float4* r0 = (const float4*)((const float*)base + (size_t)row * NN);
#pragma unroll
    for (int j = 0; j < 12; ++j) {
      float4 a = r0[lane + j * 64];
      f[j * 4 + 0] = a.x; f[j * 4 + 1] = a.y;
      f[j * 4 + 2] = a.z; f[j * 4 + 3] = a.w;
    }
  }
  if (outF8) {
    // bf path layout: f[j*8+e] = col (j*64+lane)*8 + e
    uint2* ob = (uint2*)(outF8 + (size_t)row * NN);
#pragma unroll
    for (int j = 0; j < 6; ++j) {
      uint2 w;
      w.x = pk4_f8(f[j * 8 + 0] * f8scale, f[j * 8 + 1] * f8scale,
                   f[j * 8 + 2] * f8scale, f[j * 8 + 3] * f8scale);
      w.y = pk4_f8(f[j * 8 + 4] * f8scale, f[j * 8 + 5] * f8scale,
                   f[j * 8 + 6] * f8scale, f[j * 8 + 7] * f8scale);
      ob[lane + j * 64] = w;
    }
  }
  // wave-wide OR / AND of keys -> constant-prefix skip
  unsigned bor = 0, band = 0xffffffffu;
#pragma unroll
  for (int r = 0; r < 48; ++r) {
    unsigned k = __float_as_uint(f[r]);
    bor |= k; band &= k;
  }
  for (int off = 32; off; off >>= 1) {
    bor |= (unsigned)__shfl_down((int)bor, off, 64);
    band &= (unsigned)__shfl_down((int)band, off, 64);
  }
  bor = (unsigned)__shfl((int)bor, 0, 64);
  band = (unsigned)__shfl((int)band, 0, 64);
  unsigned diff = bor ^ band;
  int hi = diff ? (31 - __clz(diff)) : 16;
  if (hi < 16) hi = 16;
  if (hi > 30) hi = 30;
  // threshold starts with the common prefix above hi
  unsigned t = band & ~((hi < 31) ? ((2u << hi) - 1u) : 0xffffffffu);

  for (int b = hi; b >= 16; --b) {
    unsigned cand = t | (1u << b);
    int c = 0;
#pragma unroll
    for (int r = 0; r < 48; ++r) c += (__float_as_uint(f[r]) >= cand) ? 1 : 0;
    for (int off = 32; off; off >>= 1) c += __shfl_down(c, off, 64);
    c = __shfl(c, 0, 64);
    if (c >= 64) t = cand;
  }
  int basec = 0;
  int* oi = outIdx + (size_t)row * 128;
  float* ov = outVal + (size_t)row * 128;
#pragma unroll
  for (int r = 0; r < 48; ++r) {
    bool keep = __float_as_uint(f[r]) >= t;
    unsigned long long m = __ballot(keep);
    if (keep) {
      int pos = basec + __popcll(m & ((1ull << lane) - 1ull));
      if (pos < 128) {
        oi[pos] = bf ? ((r >> 3) * 512 + lane * 8 + (r & 7))
                     : ((r >> 2) * 256 + lane * 4 + (r & 3));
        ov[pos] = f[r] * descale;
      }
    }
    basec += __popcll(m);
  }
  if (lane == 0) outCnt[row] = basec < 128 ? basec : 128;
}

// ---------------------------------------------------------------------------
// prep: convert A -> fp8 (straight + transposed, x2^19) + fused y1/s1
// matvec partials. grid 2304 (48x48 tiles of 64x64).
__global__ __launch_bounds__(256) void prep(
    const float* __restrict__ A, const float* __restrict__ vu,
    const float* __restrict__ vv, unsigned char* __restrict__ Af8,
    unsigned char* __restrict__ Atf8, float* __restrict__ y1,
    float* __restrict__ s1) {
  __shared__ float sh[64 * 65 + 512];
  const int bid = blockIdx.x;
  const int t = threadIdx.x;
  const int bx = (bid % 48) * 64, by = (bid / 48) * 64;
  const int rr = t >> 4;
  const int c4 = (t & 15) * 4;
  for (int it = 0; it < 4; ++it) {
    int r = rr + it * 16;
    float4 val = *(const float4*)(A + (size_t)(by + r) * NN + bx + c4);
    sh[r * 65 + c4] = val.x; sh[r * 65 + c4 + 1] = val.y;
    sh[r * 65 + c4 + 2] = val.z; sh[r * 65 + c4 + 3] = val.w;
    *(unsigned*)(Af8 + (size_t)(by + r) * NN + bx + c4) =
        pk4_f8(val.x * SCALE_A, val.y * SCALE_A, val.z * SCALE_A,
               val.w * SCALE_A);
  }
  __syncthreads();
  for (int it = 0; it < 4; ++it) {
    int c = (t >> 4) + it * 16;
    int r0 = (t & 15) * 4;
    *(unsigned*)(Atf8 + (size_t)(bx + c) * NN + by + r0) =
        pk4_f8(sh[r0 * 65 + c] * SCALE_A, sh[(r0 + 1) * 65 + c] * SCALE_A,
               sh[(r0 + 2) * 65 + c] * SCALE_A,
               sh[(r0 + 3) * 65 + c] * SCALE_A);
  }
  // fused matvec partials: y1[r] += A[r,:].v ; s1[c] += u.A[:,c]
  const int q = t >> 6;
  const int l = t & 63;
  float sy = 0.f, ss_ = 0.f;
  for (int i = 0; i < 16; ++i) {
    int c = q * 16 + i;
    sy += sh[l * 65 + c] * vv[bx + c];
    ss_ += vu[by + c] * sh[c * 65 + l];
  }
  float* red = sh + 64 * 65;
  red[q * 64 + l] = sy;
  red[256 + q * 64 + l] = ss_;
  __syncthreads();
  if (t < 64) {
    float v4 = red[t] + red[64 + t] + red[128 + t] + red[192 + t];
    atomAddF(&y1[by + t], v4);
  } else if (t < 128) {
    int cc = t - 64;
    float v4 = red[256 + cc] + red[256 + 64 + cc] + red[256 + 128 + cc] +
               red[256 + 192 + cc];
    atomAddF(&s1[bx + cc], v4);
  }
}

// ---------------------------------------------------------------------------
// fp8 GEMM: C(128x128 tile, bf16) = A(row-major fp8) * Bt(row-major fp8=B^T),
// BK=64; split-K over blockIdx.z writing separate bf16 partial buffers.
__global__ __launch_bounds__(256) void gemm_f8(
    const unsigned char* __restrict__ Ag,
    const unsigned char* __restrict__ Btg,
    unsigned short* __restrict__ Cg, int kLen) {
  __shared__ __align__(16) unsigned char As[8192];
  __shared__ __align__(16) unsigned char Bs[8192];

  const int tid = threadIdx.x;
  const int wave = tid >> 6;
  const int lane = tid & 63;
  const int rowBase = blockIdx.y * 128;
  const int colBase = blockIdx.x * 128;
  const int wr = wave >> 1, wc = wave & 1;
  const int lrow = lane & 15, lq = lane >> 4;
  const int kStart = blockIdx.z * kLen;
  unsigned short* Cout = Cg + (size_t)blockIdx.z * NN * NN;

  f32x4 acc[4][4];
  for (int i = 0; i < 4; ++i)
    for (int j = 0; j < 4; ++j) acc[i][j] = (f32x4){0.f, 0.f, 0.f, 0.f};

  const unsigned char* aS0 =
      Ag + (size_t)(rowBase + 2 * wave * 16 + lrow) * NN + lq * 16;
  const unsigned char* aS1 = aS0 + (size_t)16 * NN;
  const unsigned char* bS0 =
      Btg + (size_t)(colBase + 2 * wave * 16 + lrow) * NN + lq * 16;
  const unsigned char* bS1 = bS0 + (size_t)16 * NN;
  unsigned char* aD0 = &As[(2 * wave) * 1024];
  unsigned char* aD1 = &As[(2 * wave + 1) * 1024];
  unsigned char* bD0 = &Bs[(2 * wave) * 1024];
  unsigned char* bD1 = &Bs[(2 * wave + 1) * 1024];

  for (int kt = kStart; kt < kStart + kLen; kt += 64) {
    GLDS16(aS0 + kt, aD0);
    GLDS16(aS1 + kt, aD1);
    GLDS16(bS0 + kt, bD0);
    GLDS16(bS1 + kt, bD1);
    __syncthreads();
    for (int h = 0; h < 2; ++h) {
      const int fo = (h * 2 + (lq >> 1)) * 256 + lrow * 16 + (lq & 1) * 8;
      long af[4], bf[4];
      for (int i = 0; i < 4; ++i)
        af[i] = *(const long*)&As[(wr * 4 + i) * 1024 + fo];
      for (int j = 0; j < 4; ++j)
        bf[j] = *(const long*)&Bs[(wc * 4 + j) * 1024 + fo];
      for (int i = 0; i < 4; ++i)
        for (int j = 0; j < 4; ++j)
          acc[i][j] = __builtin_amdgcn_mfma_f32_16x16x32_fp8_fp8(
              af[i], bf[j], acc[i][j], 0, 0, 0);
    }
    __syncthreads();
  }
  // C/D layout: col = lane&15, row = (lane>>4)*4 + reg (dtype-independent)
  for (int i = 0; i < 4; ++i) {
    int r0 = rowBase + (wr * 4 + i) * 16 + lq * 4;
    for (int j = 0; j < 4; ++j) {
      int c0 = colBase + (wc * 4 + j) * 16 + lrow;
      for (int r = 0; r < 4; ++r)
        Cout[(size_t)(r0 + r) * NN + c0] = bf16bits(acc[i][j][r]);
    }
  }
}

// ---------------------------------------------------------------------------
// post1: [0,768)    topk(A2 bf16 partial-sum) + fp8 cast -> A2f8
//        [768,1536) topk(A fp32)  (layer 0)
//        [1536,2304) tvec = A.y1 (one wave per row)
__global__ __launch_bounds__(256) void post1(
    const unsigned short* __restrict__ C, int parts,
    const float* __restrict__ A, const float* __restrict__ y1,
    unsigned char* __restrict__ A2f8, int* __restrict__ cnts,
    int* __restrict__ tIdx, float* __restrict__ tVal,
    float* __restrict__ tvec) {
  const int bid = blockIdx.x;
  const int t = threadIdx.x;
  if (bid < 768) {
    int row = bid * 4 + (t >> 6);
    topk_row_dev(C, parts, 1, row, t & 63, DESCALE38, cnts + NN,
                 tIdx + (size_t)NN * 128, tVal + (size_t)NN * 128, A2f8,
                 F8SCALE2);
  } else if (bid < 1536) {
    int row = (bid - 768) * 4 + (t >> 6);
    topk_row_dev(A, 1, 0, row, t & 63, 1.0f, cnts, tIdx, tVal, nullptr, 0.f);
  } else {
    int row = (bid - 1536) * 4 + (t >> 6);
    int lane = t & 63;
    const float4* rp = (const float4*)(A + (size_t)row * NN);
    const float4* yp = (const float4*)y1;
    float s = 0.f;
#pragma unroll
    for (int j = 0; j < 12; ++j) {
      float4 a = rp[lane + j * 64];
      float4 y = yp[lane + j * 64];
      s += a.x * y.x + a.y * y.y + a.z * y.z + a.w * y.w;
    }
    for (int off = 32; off; off >>= 1) s += __shfl_down(s, off, 64);
    if (lane == 0) tvec[row] = s;
  }
}

// ---------------------------------------------------------------------------
// post2: [0,768) topk(A3 bf16 partial-sum); [768] w0..w3
__global__ __launch_bounds__(256) void post2(
    const unsigned short* __restrict__ C, int parts,
    const float* __restrict__ vu, const float* __restrict__ vv,
    const float* __restrict__ y1, const float* __restrict__ s1,
    const float* __restrict__ tvec, int* __restrict__ cnts,
    int* __restrict__ tIdx, float* __restrict__ tVal,
    float* __restrict__ wacc) {
  const int bid = blockIdx.x;
  const int t = threadIdx.x;
  if (bid < 768) {
    int row = bid * 4 + (t >> 6);
    topk_row_dev(C, parts, 1, row, t & 63, DESCALE38, cnts, tIdx, tVal,
                 nullptr, 0.f);
  } else {
    __shared__ float red4[4];
    float w0 = row_dot_f32(vu, vv, red4);  __syncthreads();
    float w1 = row_dot_f32(vu, y1, red4);  __syncthreads();
    float w2 = row_dot_f32(s1, y1, red4);  __syncthreads();
    float w3 = row_dot_f32(s1, tvec, red4);
    if (t == 0) { wacc[0] = w0; wacc[1] = w1; wacc[2] = w2; wacc[3] = w3; }
  }
}

// ---------------------------------------------------------------------------
static __device__ inline float ldE(const float* __restrict__ ue,
                                   const float* __restrict__ ie, int r, int d) {
  return r < NU ? ue[(size_t)r * DD + d] : ie[(size_t)(r - NU) * DD + d];
}

__global__ __launch_bounds__(128) void build_light(
    const float* __restrict__ uemb, const float* __restrict__ iemb,
    const float* __restrict__ uemb0, const float* __restrict__ iemb0,
    const float* __restrict__ wacc, const int* __restrict__ cnts,
    const int* __restrict__ tIdx, const float* __restrict__ tVal,
    float* __restrict__ lightOut) {
  float w0 = wacc[0], w1 = wacc[1], w2 = wacc[2], w3 = wacc[3];
  float ss = w0 + w1 + w2 + w3;
  w0 /= ss; w1 /= ss; w2 /= ss; w3 /= ss;
  float m = fmaxf(fmaxf(w0, w1), fmaxf(w2, w3));
  float e0 = expf(w0 - m), e1 = expf(w1 - m), e2 = expf(w2 - m),
        e3 = expf(w3 - m);
  float se = e0 + e1 + e2 + e3;
  float aw[4] = {e0 / se, e1 / se, e2 / se, e3 / se};
  float aw4 = GAMMA_F * (aw[1] + aw[2] + aw[3]);

  int row = blockIdx.x, d = threadIdx.x;
  float acc = aw[0] * ldE(uemb, iemb, row, d) +
              aw4 * ldE(uemb0, iemb0, row, d);
  __shared__ int sIdx[128];
  __shared__ float sVal[128];
  for (int l = 0; l < 3; ++l) {
    int c = cnts[l * NN + row];
    const int* ip = tIdx + ((size_t)l * NN + row) * 128;
    const float* vp = tVal + ((size_t)l * NN + row) * 128;
    __syncthreads();
    if (d < c) { sIdx[d] = ip[d]; sVal[d] = vp[d]; }
    __syncthreads();
    float al = aw[l + 1];
    float la = 0.f;
    for (int k = 0; k < c; ++k) la += sVal[k] * ldE(uemb, iemb, sIdx[k], d);
    acc += al * la;
  }
  lightOut[(size_t)row * DD + d] = acc;
}

__global__ __launch_bounds__(256) void out_dot(const int* __restrict__ users,
                                               const int* __restrict__ items,
                                               const float* __restrict__ lightOut,
                                               float* __restrict__ out) {
  int b = blockIdx.x * 4 + (threadIdx.x >> 6);
  int lane = threadIdx.x & 63;
  const float* up = lightOut + (size_t)users[b] * DD;
  const float* ip = lightOut + (size_t)(NU + items[b]) * DD;
  float s = up[lane] * ip[lane] + up[lane + 64] * ip[lane + 64];
  for (int off = 32; off; off >>= 1) s += __shfl_down(s, off, 64);
  if (lane == 0) out[b] = s;
}

// ---------------------------------------------------------------------------
extern "C" void kernel_launch(void* const* d_in, const int* in_sizes, int n_in,
                              void* d_out, int out_size, void* d_ws,
                              size_t ws_size, hipStream_t stream) {
  const int* users = (const int*)d_in[0];
  const int* items = (const int*)d_in[1];
  const float* A = (const float*)d_in[2];
  const float* uemb = (const float*)d_in[3];
  const float* iemb = (const float*)d_in[4];
  const float* uemb0 = (const float*)d_in[5];
  const float* iemb0 = (const float*)d_in[6];
  const float* vu = (const float*)d_in[7];
  const float* vv = (const float*)d_in[8];
  float* out = (float*)d_out;

  char* ws = (char*)d_ws;
  size_t off = 0;
  auto alloc = [&](size_t bytes) -> void* {
    void* p = ws + off;
    off += (bytes + 255) & ~(size_t)255;
    return p;
  };
  unsigned char* Af8 = (unsigned char*)alloc((size_t)NN * NN);
  unsigned char* Atf8 = (unsigned char*)alloc((size_t)NN * NN);
  unsigned char* A2f8 = (unsigned char*)alloc((size_t)NN * NN);
  float* y1 = (float*)alloc((size_t)NN * 4);   // contiguous with s1
  float* s1 = (float*)alloc((size_t)NN * 4);
  float* tvec = (float*)alloc((size_t)NN * 4);
  float* wacc = (float*)alloc(256);
  int* cnts = (int*)alloc((size_t)3 * NN * 4);
  int* tIdx = (int*)alloc((size_t)3 * NN * 128 * 4);
  float* tVal = (float*)alloc((size_t)3 * NN * 128 * 4);
  float* lightOut = (float*)alloc((size_t)NN * DD * 4);

  const size_t cBytes = (size_t)NN * NN * 2;  // bf16 partials
  int kParts = (ws_size >= off + 2 * cBytes + 512) ? 2 : 1;
  unsigned short* C = (unsigned short*)alloc((size_t)kParts * cBytes);
  const int kLen = NN / kParts;

  // 1) zero y1/s1 (contiguous 2*NN floats)
  hipMemsetAsync(y1, 0, (size_t)2 * NN * 4, stream);
  // 2) prep: A -> fp8 (straight+transposed) + y1/s1 partials (conv-only)
  prep<<<2304, 256, 0, stream>>>(A, vu, vv, Af8, Atf8, y1, s1);
  // 3) A2 = A*A (fp8 MFMA, bf16 partials x2)
  gemm_f8<<<dim3(24, 24, kParts), 256, 0, stream>>>(Af8, Atf8, C, kLen);
  // 4) post1: topk(A2)+fp8 cast | topk(A) | tvec = A.y1
  post1<<<2304, 256, 0, stream>>>(C, kParts, A, y1, A2f8, cnts, tIdx, tVal,
                                  tvec);
  // 5) A3 = A2*A (overwrite partials)
  gemm_f8<<<dim3(24, 24, kParts), 256, 0, stream>>>(A2f8, Atf8, C, kLen);
  // 6) post2: topk(A3) | w0..w3
  post2<<<769, 256, 0, stream>>>(C, kParts, vu, vv, y1, s1, tvec,
                                 cnts + 2 * NN, tIdx + (size_t)2 * NN * 128,
                                 tVal + (size_t)2 * NN * 128, wacc);
  // 7) light_out (attn softmax inlined)
  build_light<<<NN, 128, 0, stream>>>(uemb, iemb, uemb0, iemb0, wacc, cnts,
                                      tIdx, tVal, lightOut);
  // 8) gather dots
  out_dot<<<BB / 4, 256, 0, stream>>>(users, items, lightOut, out);
}